// Round 1
// baseline (1434.848 us; speedup 1.0000x reference)
//
#include <hip/hip_runtime.h>
#include <hip/hip_bf16.h>

#define N_NODES 50000
#define N_EDGES 800000
#define D 128

// -------- Kernel 1: h[dst] += val * x[src] (atomic scatter) --------
// 32 threads per edge, each thread owns 4 consecutive channels (float4).
__global__ __launch_bounds__(256) void sgcn_scatter(
    const float* __restrict__ x, const int* __restrict__ src,
    const int* __restrict__ dst, const float* __restrict__ val,
    float* __restrict__ h)
{
    long t = (long)blockIdx.x * blockDim.x + threadIdx.x;
    int e  = (int)(t >> 5);
    int cg = (int)(t & 31);
    if (e >= N_EDGES) return;
    int s = src[e];
    int d = dst[e];
    float v = val[e];
    const float4 xv = *reinterpret_cast<const float4*>(x + (long)s * D + cg * 4);
    float* hp = h + (long)d * D + cg * 4;
    unsafeAtomicAdd(hp + 0, v * xv.x);
    unsafeAtomicAdd(hp + 1, v * xv.y);
    unsafeAtomicAdd(hp + 2, v * xv.z);
    unsafeAtomicAdd(hp + 3, v * xv.w);
}

// -------- Kernel 2: WT[k][o] = W[o][k] --------
__global__ __launch_bounds__(256) void sgcn_transpose_w(
    const float* __restrict__ W, float* __restrict__ WT)
{
    int t = blockIdx.x * 256 + threadIdx.x;
    if (t < D * D) {
        int o = t / D, k = t % D;
        WT[k * D + o] = W[o * D + k];
    }
}

// -------- Kernel 3: out = relu(h @ W.T + b), WT staged in LDS --------
// 256 threads = 4 waves; each wave handles 2 nodes; each lane 2 outputs/node.
__global__ __launch_bounds__(256) void sgcn_gemm_relu(
    const float* __restrict__ h, const float* __restrict__ WT,
    const float* __restrict__ bias, float* __restrict__ out)
{
    __shared__ float wt[D * D];  // 64 KB -> 2 blocks/CU
    const float4* WT4 = reinterpret_cast<const float4*>(WT);
    float4* wt4 = reinterpret_cast<float4*>(wt);
    for (int i = threadIdx.x; i < D * D / 4; i += 256) wt4[i] = WT4[i];
    __syncthreads();

    int wave = threadIdx.x >> 6;
    int lane = threadIdx.x & 63;
    int n0 = (blockIdx.x * 4 + wave) * 2;  // grid chosen so n0+1 < N_NODES always
    if (n0 >= N_NODES) return;

    const float4* h04 = reinterpret_cast<const float4*>(h + (long)n0 * D);
    const float4* h14 = reinterpret_cast<const float4*>(h + (long)(n0 + 1) * D);

    float acc00 = 0.f, acc01 = 0.f, acc10 = 0.f, acc11 = 0.f;
#pragma unroll 4
    for (int k4 = 0; k4 < D / 4; ++k4) {
        float4 a = h04[k4];
        float4 c = h14[k4];
        int k = k4 * 4;
#pragma unroll
        for (int j = 0; j < 4; ++j) {
            float aj = (j == 0) ? a.x : (j == 1) ? a.y : (j == 2) ? a.z : a.w;
            float cj = (j == 0) ? c.x : (j == 1) ? c.y : (j == 2) ? c.z : c.w;
            float w0 = wt[(k + j) * D + lane];
            float w1 = wt[(k + j) * D + 64 + lane];
            acc00 += aj * w0; acc01 += aj * w1;
            acc10 += cj * w0; acc11 += cj * w1;
        }
    }
    float b0 = bias[lane], b1 = bias[64 + lane];
    long o0 = (long)n0 * D;
    out[o0 + lane]           = fmaxf(acc00 + b0, 0.f);
    out[o0 + 64 + lane]      = fmaxf(acc01 + b1, 0.f);
    out[o0 + D + lane]       = fmaxf(acc10 + b0, 0.f);
    out[o0 + D + 64 + lane]  = fmaxf(acc11 + b1, 0.f);
}

extern "C" void kernel_launch(void* const* d_in, const int* in_sizes, int n_in,
                              void* d_out, int out_size, void* d_ws, size_t ws_size,
                              hipStream_t stream) {
    const float* x   = (const float*)d_in[0];
    const int*   es  = (const int*)d_in[1];
    const int*   ed  = (const int*)d_in[2];
    const float* ev  = (const float*)d_in[3];
    const float* W   = (const float*)d_in[4];
    const float* b   = (const float*)d_in[5];
    float* out = (float*)d_out;

    float* h  = (float*)d_ws;                       // N_NODES*D floats = 25.6 MB
    float* WT = h + (size_t)N_NODES * D;            // 64 KB

    hipMemsetAsync(h, 0, (size_t)N_NODES * D * sizeof(float), stream);

    sgcn_transpose_w<<<(D * D + 255) / 256, 256, 0, stream>>>(W, WT);

    long scatter_threads = (long)N_EDGES * 32;
    int scatter_blocks = (int)((scatter_threads + 255) / 256);
    sgcn_scatter<<<scatter_blocks, 256, 0, stream>>>(x, es, ed, ev, h);

    sgcn_gemm_relu<<<(N_NODES / 2 + 3) / 4, 256, 0, stream>>>(h, WT, b, out);
}

// Round 2
// 327.413 us; speedup vs baseline: 4.3824x; 4.3824x over previous
//
#include <hip/hip_runtime.h>
#include <hip/hip_bf16.h>

#define N_NODES 50000
#define N_EDGES 800000
#define D 128

// ---------------- CSR build ----------------

__global__ __launch_bounds__(256) void sgcn_hist(
    const int* __restrict__ dst, int* __restrict__ deg)
{
    int t = blockIdx.x * 256 + threadIdx.x;
    int stride = gridDim.x * 256;
    for (int e = t; e < N_EDGES; e += stride)
        atomicAdd(&deg[dst[e]], 1);
}

// Single block, 1024 threads: exclusive scan of deg[50000] -> rowptr[50001], cursor copy.
__global__ __launch_bounds__(1024) void sgcn_scan(
    const int* __restrict__ deg, int* __restrict__ rowptr, int* __restrict__ cursor)
{
    __shared__ int part[1024];
    int t = threadIdx.x;
    const int C = (N_NODES + 1023) / 1024;  // 49
    int s0 = t * C;
    int s1 = s0 + C; if (s1 > N_NODES) s1 = N_NODES; if (s0 > N_NODES) s0 = N_NODES;
    int sum = 0;
    for (int i = s0; i < s1; ++i) sum += deg[i];
    part[t] = sum;
    __syncthreads();
    for (int off = 1; off < 1024; off <<= 1) {
        int mine  = part[t];
        int other = (t >= off) ? part[t - off] : 0;
        __syncthreads();
        part[t] = mine + other;
        __syncthreads();
    }
    int run = (t == 0) ? 0 : part[t - 1];
    for (int i = s0; i < s1; ++i) {
        int dg = deg[i];
        rowptr[i] = run;
        cursor[i] = run;
        run += dg;
    }
    if (t == 1023) rowptr[N_NODES] = part[1023];
}

__global__ __launch_bounds__(256) void sgcn_permute(
    const int* __restrict__ src, const int* __restrict__ dst,
    const float* __restrict__ val, int* __restrict__ cursor,
    int* __restrict__ esrc, float* __restrict__ eval)
{
    int t = blockIdx.x * 256 + threadIdx.x;
    int stride = gridDim.x * 256;
    for (int e = t; e < N_EDGES; e += stride) {
        int d = dst[e];
        int pos = atomicAdd(&cursor[d], 1);
        esrc[pos] = src[e];
        eval[pos] = val[e];
    }
}

// ---------------- Aggregation: wave per node, lane owns 2 channels ----------------

__global__ __launch_bounds__(256) void sgcn_aggregate(
    const float* __restrict__ x, const int* __restrict__ rowptr,
    const int* __restrict__ esrc, const float* __restrict__ eval,
    float* __restrict__ h)
{
    int gw    = (blockIdx.x * 256 + threadIdx.x) >> 6;
    int lane  = threadIdx.x & 63;
    int nW    = (gridDim.x * 256) >> 6;
    for (int n = gw; n < N_NODES; n += nW) {
        int j0 = rowptr[n], j1 = rowptr[n + 1];
        float ax = 0.f, ay = 0.f;
        int j = j0;
        for (; j + 4 <= j1; j += 4) {
            int s0 = esrc[j], s1 = esrc[j + 1], s2 = esrc[j + 2], s3 = esrc[j + 3];
            float v0 = eval[j], v1 = eval[j + 1], v2 = eval[j + 2], v3 = eval[j + 3];
            float2 a = *reinterpret_cast<const float2*>(x + (long)s0 * D + lane * 2);
            float2 b = *reinterpret_cast<const float2*>(x + (long)s1 * D + lane * 2);
            float2 c = *reinterpret_cast<const float2*>(x + (long)s2 * D + lane * 2);
            float2 d = *reinterpret_cast<const float2*>(x + (long)s3 * D + lane * 2);
            ax += v0 * a.x + v1 * b.x + v2 * c.x + v3 * d.x;
            ay += v0 * a.y + v1 * b.y + v2 * c.y + v3 * d.y;
        }
        for (; j < j1; ++j) {
            int s = esrc[j];
            float v = eval[j];
            float2 a = *reinterpret_cast<const float2*>(x + (long)s * D + lane * 2);
            ax += v * a.x;
            ay += v * a.y;
        }
        float2 r; r.x = ax; r.y = ay;
        *reinterpret_cast<float2*>(h + (long)n * D + lane * 2) = r;
    }
}

// ---------------- W transpose + GEMM(relu) ----------------

__global__ __launch_bounds__(256) void sgcn_transpose_w(
    const float* __restrict__ W, float* __restrict__ WT)
{
    int t = blockIdx.x * 256 + threadIdx.x;
    if (t < D * D) {
        int o = t / D, k = t % D;
        WT[k * D + o] = W[o * D + k];
    }
}

// 256 threads = 4 waves; W^T staged in LDS once per block; node grid-stride loop.
__global__ __launch_bounds__(256) void sgcn_gemm_relu(
    const float* __restrict__ h, const float* __restrict__ WT,
    const float* __restrict__ bias, float* __restrict__ out)
{
    __shared__ float wt[D * D];  // 64 KB
    const float4* WT4 = reinterpret_cast<const float4*>(WT);
    float4* wt4 = reinterpret_cast<float4*>(wt);
    for (int i = threadIdx.x; i < D * D / 4; i += 256) wt4[i] = WT4[i];
    __syncthreads();

    int wave = threadIdx.x >> 6;
    int lane = threadIdx.x & 63;
    int gw = blockIdx.x * 4 + wave;
    int nW = gridDim.x * 4;
    float b0 = bias[lane], b1 = bias[64 + lane];

    for (int n0 = gw * 2; n0 < N_NODES; n0 += nW * 2) {  // N_NODES even -> n0+1 valid
        const float4* h04 = reinterpret_cast<const float4*>(h + (long)n0 * D);
        const float4* h14 = reinterpret_cast<const float4*>(h + (long)(n0 + 1) * D);
        float acc00 = 0.f, acc01 = 0.f, acc10 = 0.f, acc11 = 0.f;
#pragma unroll 4
        for (int k4 = 0; k4 < D / 4; ++k4) {
            float4 a = h04[k4];
            float4 c = h14[k4];
            int k = k4 * 4;
#pragma unroll
            for (int j = 0; j < 4; ++j) {
                float aj = (j == 0) ? a.x : (j == 1) ? a.y : (j == 2) ? a.z : a.w;
                float cj = (j == 0) ? c.x : (j == 1) ? c.y : (j == 2) ? c.z : c.w;
                float w0 = wt[(k + j) * D + lane];
                float w1 = wt[(k + j) * D + 64 + lane];
                acc00 += aj * w0; acc01 += aj * w1;
                acc10 += cj * w0; acc11 += cj * w1;
            }
        }
        long o0 = (long)n0 * D;
        out[o0 + lane]          = fmaxf(acc00 + b0, 0.f);
        out[o0 + 64 + lane]     = fmaxf(acc01 + b1, 0.f);
        out[o0 + D + lane]      = fmaxf(acc10 + b0, 0.f);
        out[o0 + D + 64 + lane] = fmaxf(acc11 + b1, 0.f);
    }
}

// ---------------- Fallback (round-1 atomic path) if ws too small ----------------

__global__ __launch_bounds__(256) void sgcn_scatter(
    const float* __restrict__ x, const int* __restrict__ src,
    const int* __restrict__ dst, const float* __restrict__ val,
    float* __restrict__ h)
{
    long t = (long)blockIdx.x * blockDim.x + threadIdx.x;
    int e  = (int)(t >> 5);
    int cg = (int)(t & 31);
    if (e >= N_EDGES) return;
    int s = src[e];
    int d = dst[e];
    float v = val[e];
    const float4 xv = *reinterpret_cast<const float4*>(x + (long)s * D + cg * 4);
    float* hp = h + (long)d * D + cg * 4;
    unsafeAtomicAdd(hp + 0, v * xv.x);
    unsafeAtomicAdd(hp + 1, v * xv.y);
    unsafeAtomicAdd(hp + 2, v * xv.z);
    unsafeAtomicAdd(hp + 3, v * xv.w);
}

extern "C" void kernel_launch(void* const* d_in, const int* in_sizes, int n_in,
                              void* d_out, int out_size, void* d_ws, size_t ws_size,
                              hipStream_t stream) {
    const float* x   = (const float*)d_in[0];
    const int*   es  = (const int*)d_in[1];
    const int*   ed  = (const int*)d_in[2];
    const float* ev  = (const float*)d_in[3];
    const float* W   = (const float*)d_in[4];
    const float* b   = (const float*)d_in[5];
    float* out = (float*)d_out;

    // Workspace layout (all 4-byte typed)
    char* ws = (char*)d_ws;
    size_t off = 0;
    float* h      = (float*)(ws + off); off += (size_t)N_NODES * D * sizeof(float);   // 25.6 MB
    float* WT     = (float*)(ws + off); off += (size_t)D * D * sizeof(float);          // 64 KB
    float* eval_s = (float*)(ws + off); off += (size_t)N_EDGES * sizeof(float);        // 3.2 MB
    int*   esrc_s = (int*)  (ws + off); off += (size_t)N_EDGES * sizeof(int);          // 3.2 MB
    int*   rowptr = (int*)  (ws + off); off += (size_t)(N_NODES + 1) * sizeof(int);
    int*   cursor = (int*)  (ws + off); off += (size_t)N_NODES * sizeof(int);
    int*   deg    = (int*)  (ws + off); off += (size_t)N_NODES * sizeof(int);
    size_t needed = off;

    sgcn_transpose_w<<<(D * D + 255) / 256, 256, 0, stream>>>(W, WT);

    if (ws_size >= needed) {
        // CSR path: no float atomics.
        hipMemsetAsync(deg, 0, (size_t)N_NODES * sizeof(int), stream);
        sgcn_hist<<<1024, 256, 0, stream>>>(ed, deg);
        sgcn_scan<<<1, 1024, 0, stream>>>(deg, rowptr, cursor);
        sgcn_permute<<<1024, 256, 0, stream>>>(es, ed, ev, cursor, esrc_s, eval_s);
        sgcn_aggregate<<<2048, 256, 0, stream>>>(x, rowptr, esrc_s, eval_s, h);
    } else {
        // Fallback: atomic scatter.
        hipMemsetAsync(h, 0, (size_t)N_NODES * D * sizeof(float), stream);
        long scatter_threads = (long)N_EDGES * 32;
        int scatter_blocks = (int)((scatter_threads + 255) / 256);
        sgcn_scatter<<<scatter_blocks, 256, 0, stream>>>(x, es, ed, ev, h);
    }

    sgcn_gemm_relu<<<512, 256, 0, stream>>>(h, WT, b, out);
}

// Round 3
// 180.503 us; speedup vs baseline: 7.9492x; 1.8139x over previous
//
#include <hip/hip_runtime.h>
#include <hip/hip_bf16.h>

#define N_NODES 50000
#define N_EDGES 800000
#define D 128
#define SCAN_NB 49  // ceil(50000/1024)

// ---------------- CSR build ----------------

// rank[e] = arrival order of edge e within its dst bucket; deg[d] = degree.
__global__ __launch_bounds__(256) void sgcn_hist_rank(
    const int* __restrict__ dst, int* __restrict__ deg, int* __restrict__ rank)
{
    int e = blockIdx.x * 256 + threadIdx.x;
    if (e < N_EDGES)
        rank[e] = atomicAdd(&deg[dst[e]], 1);
}

// Per-block reduce of deg (1024 elements / block, int4 loads).
__global__ __launch_bounds__(256) void sgcn_scan1(
    const int* __restrict__ deg, int* __restrict__ blockSum)
{
    __shared__ int red[256];
    int tid = threadIdx.x;
    int base = blockIdx.x * 1024 + tid * 4;
    int4 v = make_int4(0, 0, 0, 0);
    if (base < N_NODES) v = *reinterpret_cast<const int4*>(deg + base);  // N_NODES % 4 == 0
    red[tid] = v.x + v.y + v.z + v.w;
    __syncthreads();
    for (int off = 128; off > 0; off >>= 1) {
        if (tid < off) red[tid] += red[tid + off];
        __syncthreads();
    }
    if (tid == 0) blockSum[blockIdx.x] = red[0];
}

// Single wave: exclusive scan of SCAN_NB block sums; writes rowptr[N_NODES].
__global__ __launch_bounds__(64) void sgcn_scan2(
    const int* __restrict__ blockSum, int* __restrict__ blockOff, int* __restrict__ rowptr)
{
    int t = threadIdx.x;
    int mine = (t < SCAN_NB) ? blockSum[t] : 0;
    int v = mine;
    for (int off = 1; off < 64; off <<= 1) {
        int u = __shfl_up(v, off);
        if (t >= off) v += u;
    }
    if (t < SCAN_NB) blockOff[t] = v - mine;
    if (t == 63) rowptr[N_NODES] = v;
}

// Per-block exclusive rescan + block offset -> rowptr.
__global__ __launch_bounds__(256) void sgcn_scan3(
    const int* __restrict__ deg, const int* __restrict__ blockOff,
    int* __restrict__ rowptr)
{
    __shared__ int part[256];
    int tid = threadIdx.x;
    int base = blockIdx.x * 1024 + tid * 4;
    int4 v = make_int4(0, 0, 0, 0);
    if (base < N_NODES) v = *reinterpret_cast<const int4*>(deg + base);
    int s = v.x + v.y + v.z + v.w;
    part[tid] = s;
    __syncthreads();
    for (int off = 1; off < 256; off <<= 1) {
        int mine  = part[tid];
        int other = (tid >= off) ? part[tid - off] : 0;
        __syncthreads();
        part[tid] = mine + other;
        __syncthreads();
    }
    int run = blockOff[blockIdx.x] + ((tid == 0) ? 0 : part[tid - 1]);
    if (base < N_NODES) {
        int4 r;
        r.x = run;
        r.y = run + v.x;
        r.z = r.y + v.y;
        r.w = r.z + v.z;
        *reinterpret_cast<int4*>(rowptr + base) = r;
    }
}

// Scatter edges into dst-sorted order: pos = rowptr[dst] + rank. No atomics.
__global__ __launch_bounds__(256) void sgcn_permute(
    const int* __restrict__ src, const int* __restrict__ dst,
    const float* __restrict__ val, const int* __restrict__ rowptr,
    const int* __restrict__ rank, int2* __restrict__ epair)
{
    int e = blockIdx.x * 256 + threadIdx.x;
    if (e < N_EDGES) {
        int pos = rowptr[dst[e]] + rank[e];
        int2 p;
        p.x = src[e];
        p.y = __float_as_int(val[e]);
        epair[pos] = p;
    }
}

// ---------------- Aggregation: wave per node, lane owns 2 channels ----------------

__global__ __launch_bounds__(256) void sgcn_aggregate(
    const float* __restrict__ x, const int* __restrict__ rowptr,
    const int2* __restrict__ epair, float* __restrict__ h)
{
    int gw   = (blockIdx.x * 256 + threadIdx.x) >> 6;
    int lane = threadIdx.x & 63;
    int nW   = (gridDim.x * 256) >> 6;
    for (int n = gw; n < N_NODES; n += nW) {
        int j0 = rowptr[n], j1 = rowptr[n + 1];
        float ax = 0.f, ay = 0.f;
        int j = j0;
        for (; j + 4 <= j1; j += 4) {
            int2 p0 = epair[j], p1 = epair[j + 1], p2 = epair[j + 2], p3 = epair[j + 3];
            float2 a = *reinterpret_cast<const float2*>(x + (long)p0.x * D + lane * 2);
            float2 b = *reinterpret_cast<const float2*>(x + (long)p1.x * D + lane * 2);
            float2 c = *reinterpret_cast<const float2*>(x + (long)p2.x * D + lane * 2);
            float2 d = *reinterpret_cast<const float2*>(x + (long)p3.x * D + lane * 2);
            float v0 = __int_as_float(p0.y), v1 = __int_as_float(p1.y);
            float v2 = __int_as_float(p2.y), v3 = __int_as_float(p3.y);
            ax += v0 * a.x + v1 * b.x + v2 * c.x + v3 * d.x;
            ay += v0 * a.y + v1 * b.y + v2 * c.y + v3 * d.y;
        }
        for (; j < j1; ++j) {
            int2 p = epair[j];
            float v = __int_as_float(p.y);
            float2 a = *reinterpret_cast<const float2*>(x + (long)p.x * D + lane * 2);
            ax += v * a.x;
            ay += v * a.y;
        }
        float2 r; r.x = ax; r.y = ay;
        *reinterpret_cast<float2*>(h + (long)n * D + lane * 2) = r;
    }
}

// ---------------- W transpose + GEMM(relu) ----------------

__global__ __launch_bounds__(256) void sgcn_transpose_w(
    const float* __restrict__ W, float* __restrict__ WT)
{
    int t = blockIdx.x * 256 + threadIdx.x;
    if (t < D * D) {
        int o = t / D, k = t % D;
        WT[k * D + o] = W[o * D + k];
    }
}

__global__ __launch_bounds__(256) void sgcn_gemm_relu(
    const float* __restrict__ h, const float* __restrict__ WT,
    const float* __restrict__ bias, float* __restrict__ out)
{
    __shared__ float wt[D * D];  // 64 KB -> 2 blocks/CU
    const float4* WT4 = reinterpret_cast<const float4*>(WT);
    float4* wt4 = reinterpret_cast<float4*>(wt);
    for (int i = threadIdx.x; i < D * D / 4; i += 256) wt4[i] = WT4[i];
    __syncthreads();

    int wave = threadIdx.x >> 6;
    int lane = threadIdx.x & 63;
    int gw = blockIdx.x * 4 + wave;
    int nW = gridDim.x * 4;
    float b0 = bias[lane], b1 = bias[64 + lane];

    for (int n0 = gw * 2; n0 < N_NODES; n0 += nW * 2) {  // N_NODES even
        const float4* h04 = reinterpret_cast<const float4*>(h + (long)n0 * D);
        const float4* h14 = reinterpret_cast<const float4*>(h + (long)(n0 + 1) * D);
        float acc00 = 0.f, acc01 = 0.f, acc10 = 0.f, acc11 = 0.f;
#pragma unroll 4
        for (int k4 = 0; k4 < D / 4; ++k4) {
            float4 a = h04[k4];
            float4 c = h14[k4];
            int k = k4 * 4;
#pragma unroll
            for (int j = 0; j < 4; ++j) {
                float aj = (j == 0) ? a.x : (j == 1) ? a.y : (j == 2) ? a.z : a.w;
                float cj = (j == 0) ? c.x : (j == 1) ? c.y : (j == 2) ? c.z : c.w;
                float w0 = wt[(k + j) * D + lane];
                float w1 = wt[(k + j) * D + 64 + lane];
                acc00 += aj * w0; acc01 += aj * w1;
                acc10 += cj * w0; acc11 += cj * w1;
            }
        }
        long o0 = (long)n0 * D;
        out[o0 + lane]          = fmaxf(acc00 + b0, 0.f);
        out[o0 + 64 + lane]     = fmaxf(acc01 + b1, 0.f);
        out[o0 + D + lane]      = fmaxf(acc10 + b0, 0.f);
        out[o0 + D + 64 + lane] = fmaxf(acc11 + b1, 0.f);
    }
}

// ---------------- Fallback (atomic path) if ws too small ----------------

__global__ __launch_bounds__(256) void sgcn_scatter(
    const float* __restrict__ x, const int* __restrict__ src,
    const int* __restrict__ dst, const float* __restrict__ val,
    float* __restrict__ h)
{
    long t = (long)blockIdx.x * blockDim.x + threadIdx.x;
    int e  = (int)(t >> 5);
    int cg = (int)(t & 31);
    if (e >= N_EDGES) return;
    int s = src[e];
    int d = dst[e];
    float v = val[e];
    const float4 xv = *reinterpret_cast<const float4*>(x + (long)s * D + cg * 4);
    float* hp = h + (long)d * D + cg * 4;
    unsafeAtomicAdd(hp + 0, v * xv.x);
    unsafeAtomicAdd(hp + 1, v * xv.y);
    unsafeAtomicAdd(hp + 2, v * xv.z);
    unsafeAtomicAdd(hp + 3, v * xv.w);
}

extern "C" void kernel_launch(void* const* d_in, const int* in_sizes, int n_in,
                              void* d_out, int out_size, void* d_ws, size_t ws_size,
                              hipStream_t stream) {
    const float* x   = (const float*)d_in[0];
    const int*   es  = (const int*)d_in[1];
    const int*   ed  = (const int*)d_in[2];
    const float* ev  = (const float*)d_in[3];
    const float* W   = (const float*)d_in[4];
    const float* b   = (const float*)d_in[5];
    float* out = (float*)d_out;

    // Workspace layout (16B-aligned fields)
    char* ws = (char*)d_ws;
    size_t off = 0;
    float* h        = (float*)(ws + off); off += (size_t)N_NODES * D * sizeof(float);   // 25.6 MB
    float* WT       = (float*)(ws + off); off += (size_t)D * D * sizeof(float);         // 64 KB
    int2*  epair    = (int2*) (ws + off); off += (size_t)N_EDGES * sizeof(int2);        // 6.4 MB
    int*   rowptr   = (int*)  (ws + off); off += ((size_t)(N_NODES + 1) * sizeof(int) + 15) & ~15ull;
    int*   deg      = (int*)  (ws + off); off += (size_t)N_NODES * sizeof(int);
    int*   blockSum = (int*)  (ws + off); off += 64 * sizeof(int);
    int*   blockOff = (int*)  (ws + off); off += 64 * sizeof(int);
    size_t needed = off;
    // rank overlays h: rank is dead before sgcn_aggregate (first writer of h) runs.
    int* rank = (int*)h;

    sgcn_transpose_w<<<(D * D + 255) / 256, 256, 0, stream>>>(W, WT);

    if (ws_size >= needed) {
        const int EB = (N_EDGES + 255) / 256;  // 3125
        hipMemsetAsync(deg, 0, (size_t)N_NODES * sizeof(int), stream);
        sgcn_hist_rank<<<EB, 256, 0, stream>>>(ed, deg, rank);
        sgcn_scan1<<<SCAN_NB, 256, 0, stream>>>(deg, blockSum);
        sgcn_scan2<<<1, 64, 0, stream>>>(blockSum, blockOff, rowptr);
        sgcn_scan3<<<SCAN_NB, 256, 0, stream>>>(deg, blockOff, rowptr);
        sgcn_permute<<<EB, 256, 0, stream>>>(es, ed, ev, rowptr, rank, epair);
        sgcn_aggregate<<<2048, 256, 0, stream>>>(x, rowptr, epair, h);
    } else {
        hipMemsetAsync(h, 0, (size_t)N_NODES * D * sizeof(float), stream);
        long scatter_threads = (long)N_EDGES * 32;
        int scatter_blocks = (int)((scatter_threads + 255) / 256);
        sgcn_scatter<<<scatter_blocks, 256, 0, stream>>>(x, es, ed, ev, h);
    }

    sgcn_gemm_relu<<<512, 256, 0, stream>>>(h, WT, b, out);
}

// Round 5
// 123.392 us; speedup vs baseline: 11.6284x; 1.4628x over previous
//
#include <hip/hip_runtime.h>
#include <hip/hip_bf16.h>

#define N_NODES 50000
#define N_EDGES 800000
#define D 128
#define SCAN_NB 49  // ceil(50000/1024)

typedef __attribute__((ext_vector_type(8))) short short8;
typedef __attribute__((ext_vector_type(4))) float f32x4;
typedef unsigned int uint;
typedef unsigned short ushort;

__device__ __forceinline__ ushort f2bf(float f) {
    // float -> bf16 bits, round-to-nearest-even
    uint u = __float_as_uint(f);
    u += 0x7fffu + ((u >> 16) & 1u);
    return (ushort)(u >> 16);
}

// ---------------- dtype conversion ----------------

__global__ __launch_bounds__(256) void sgcn_conv_x(
    const float* __restrict__ x, ushort* __restrict__ xb)
{
    int t = blockIdx.x * 256 + threadIdx.x;
    if (t >= (N_NODES * D) / 8) return;
    const float4* x4 = reinterpret_cast<const float4*>(x);
    float4 a = x4[2 * t], b = x4[2 * t + 1];
    short8 s;
    s[0] = (short)f2bf(a.x); s[1] = (short)f2bf(a.y);
    s[2] = (short)f2bf(a.z); s[3] = (short)f2bf(a.w);
    s[4] = (short)f2bf(b.x); s[5] = (short)f2bf(b.y);
    s[6] = (short)f2bf(b.z); s[7] = (short)f2bf(b.w);
    *reinterpret_cast<short8*>(xb + (size_t)t * 8) = s;
}

__global__ __launch_bounds__(256) void sgcn_conv_w(
    const float* __restrict__ W, ushort* __restrict__ Wb)
{
    int t = blockIdx.x * 256 + threadIdx.x;
    if (t >= (D * D) / 4) return;
    float4 a = reinterpret_cast<const float4*>(W)[t];
    ushort4 s;
    s.x = f2bf(a.x); s.y = f2bf(a.y); s.z = f2bf(a.z); s.w = f2bf(a.w);
    *reinterpret_cast<ushort4*>(Wb + (size_t)t * 4) = s;
}

// ---------------- CSR build ----------------

__global__ __launch_bounds__(256) void sgcn_hist_rank(
    const int* __restrict__ dst, int* __restrict__ deg, int* __restrict__ rank)
{
    int e = blockIdx.x * 256 + threadIdx.x;
    if (e < N_EDGES)
        rank[e] = atomicAdd(&deg[dst[e]], 1);
}

__global__ __launch_bounds__(256) void sgcn_scan1(
    const int* __restrict__ deg, int* __restrict__ blockSum)
{
    __shared__ int red[256];
    int tid = threadIdx.x;
    int base = blockIdx.x * 1024 + tid * 4;
    int4 v = make_int4(0, 0, 0, 0);
    if (base < N_NODES) v = *reinterpret_cast<const int4*>(deg + base);
    red[tid] = v.x + v.y + v.z + v.w;
    __syncthreads();
    for (int off = 128; off > 0; off >>= 1) {
        if (tid < off) red[tid] += red[tid + off];
        __syncthreads();
    }
    if (tid == 0) blockSum[blockIdx.x] = red[0];
}

__global__ __launch_bounds__(64) void sgcn_scan2(
    const int* __restrict__ blockSum, int* __restrict__ blockOff, int* __restrict__ rowptr)
{
    int t = threadIdx.x;
    int mine = (t < SCAN_NB) ? blockSum[t] : 0;
    int v = mine;
    for (int off = 1; off < 64; off <<= 1) {
        int u = __shfl_up(v, off);
        if (t >= off) v += u;
    }
    if (t < SCAN_NB) blockOff[t] = v - mine;
    if (t == 63) rowptr[N_NODES] = v;
}

__global__ __launch_bounds__(256) void sgcn_scan3(
    const int* __restrict__ deg, const int* __restrict__ blockOff,
    int* __restrict__ rowptr)
{
    __shared__ int part[256];
    int tid = threadIdx.x;
    int base = blockIdx.x * 1024 + tid * 4;
    int4 v = make_int4(0, 0, 0, 0);
    if (base < N_NODES) v = *reinterpret_cast<const int4*>(deg + base);
    int s = v.x + v.y + v.z + v.w;
    part[tid] = s;
    __syncthreads();
    for (int off = 1; off < 256; off <<= 1) {
        int mine  = part[tid];
        int other = (tid >= off) ? part[tid - off] : 0;
        __syncthreads();
        part[tid] = mine + other;
        __syncthreads();
    }
    int run = blockOff[blockIdx.x] + ((tid == 0) ? 0 : part[tid - 1]);
    if (base < N_NODES) {
        int4 r;
        r.x = run;
        r.y = run + v.x;
        r.z = r.y + v.y;
        r.w = r.z + v.z;
        *reinterpret_cast<int4*>(rowptr + base) = r;
    }
}

__global__ __launch_bounds__(256) void sgcn_permute(
    const int* __restrict__ src, const int* __restrict__ dst,
    const float* __restrict__ val, const int* __restrict__ rowptr,
    const int* __restrict__ rank, int2* __restrict__ epair)
{
    int e = blockIdx.x * 256 + threadIdx.x;
    if (e < N_EDGES) {
        int pos = rowptr[dst[e]] + rank[e];
        int2 p;
        p.x = src[e];
        p.y = __float_as_int(val[e]);
        epair[pos] = p;
    }
}

// ---------------- Aggregation: wave per node, bf16 gather ----------------
// xb/hb are [N][64] uints, each uint = channels {2*lane, 2*lane+1} packed bf16.

__device__ __forceinline__ float bflo(uint u) { return __uint_as_float(u << 16); }
__device__ __forceinline__ float bfhi(uint u) { return __uint_as_float(u & 0xffff0000u); }

__global__ __launch_bounds__(256) void sgcn_aggregate(
    const uint* __restrict__ xb, const int* __restrict__ rowptr,
    const int2* __restrict__ epair, uint* __restrict__ hb)
{
    int gw   = (blockIdx.x * 256 + threadIdx.x) >> 6;
    int lane = threadIdx.x & 63;
    int nW   = (gridDim.x * 256) >> 6;
    for (int n = gw; n < N_NODES; n += nW) {
        int j0 = rowptr[n], j1 = rowptr[n + 1];
        float ax = 0.f, ay = 0.f;
        int j = j0;
        for (; j + 8 <= j1; j += 8) {
#pragma unroll
            for (int q = 0; q < 8; ++q) {
                int2 p = epair[j + q];
                uint u = xb[(long)p.x * 64 + lane];
                float v = __int_as_float(p.y);
                ax += v * bflo(u);
                ay += v * bfhi(u);
            }
        }
        for (; j < j1; ++j) {
            int2 p = epair[j];
            uint u = xb[(long)p.x * 64 + lane];
            float v = __int_as_float(p.y);
            ax += v * bflo(u);
            ay += v * bfhi(u);
        }
        hb[(long)n * 64 + lane] = (uint)f2bf(ax) | ((uint)f2bf(ay) << 16);
    }
}

// ---------------- MFMA GEMM: out = relu(H @ W^T + b) ----------------
// Wave computes a 16-row x 128-col stripe. A lane(l): holds H[m0+(l&15)][kb*8+j].
// B lane(l): holds B[k][n] = W[n][k] with n = n0+(l&15), k = kb*8+j -> contiguous
// read of row-major W. C/D: col = l&15 (n), row = (l>>4)*4 + r (m). [m89 layout]

__global__ __launch_bounds__(256) void sgcn_gemm_mfma(
    const short* __restrict__ Hb, const short* __restrict__ Wb,
    const float* __restrict__ bias, float* __restrict__ out)
{
    int wave = threadIdx.x >> 6;
    int lane = threadIdx.x & 63;
    int lm = lane & 15;
    int kb = lane >> 4;

    // Preload all B fragments (8 n-tiles x 4 k-blocks) and bias into registers.
    short8 bfr[8][4];
#pragma unroll
    for (int nt = 0; nt < 8; ++nt)
#pragma unroll
        for (int kk = 0; kk < 4; ++kk)
            bfr[nt][kk] = *reinterpret_cast<const short8*>(
                Wb + (nt * 16 + lm) * D + kk * 32 + kb * 8);
    float bv[8];
#pragma unroll
    for (int nt = 0; nt < 8; ++nt) bv[nt] = bias[nt * 16 + lm];

    const int nMT = N_NODES / 16;  // 3125
    int mt0 = blockIdx.x * 4 + wave;
    int strideMT = gridDim.x * 4;
    for (int mt = mt0; mt < nMT; mt += strideMT) {
        int m0 = mt * 16;
        const short* hrow = Hb + (long)(m0 + lm) * D + kb * 8;
        short8 afr[4];
#pragma unroll
        for (int kk = 0; kk < 4; ++kk)
            afr[kk] = *reinterpret_cast<const short8*>(hrow + kk * 32);
#pragma unroll
        for (int nt = 0; nt < 8; ++nt) {
            f32x4 acc = {0.f, 0.f, 0.f, 0.f};
#pragma unroll
            for (int kk = 0; kk < 4; ++kk)
                acc = __builtin_amdgcn_mfma_f32_16x16x32_bf16(afr[kk], bfr[nt][kk], acc, 0, 0, 0);
            float* op = out + (long)(m0 + kb * 4) * D + nt * 16 + lm;
#pragma unroll
            for (int r = 0; r < 4; ++r)
                op[(long)r * D] = fmaxf(acc[r] + bv[nt], 0.f);
        }
    }
}

extern "C" void kernel_launch(void* const* d_in, const int* in_sizes, int n_in,
                              void* d_out, int out_size, void* d_ws, size_t ws_size,
                              hipStream_t stream) {
    const float* x   = (const float*)d_in[0];
    const int*   es  = (const int*)d_in[1];
    const int*   ed  = (const int*)d_in[2];
    const float* ev  = (const float*)d_in[3];
    const float* W   = (const float*)d_in[4];
    const float* b   = (const float*)d_in[5];
    float* out = (float*)d_out;

    // Workspace layout (16B-aligned fields), total ~32.4 MB
    char* ws = (char*)d_ws;
    size_t off = 0;
    uint*   hb       = (uint*)  (ws + off); off += (size_t)N_NODES * (D / 2) * sizeof(uint);   // 12.8 MB
    uint*   xb       = (uint*)  (ws + off); off += (size_t)N_NODES * (D / 2) * sizeof(uint);   // 12.8 MB
    ushort* Wb       = (ushort*)(ws + off); off += (size_t)D * D * sizeof(ushort);             // 32 KB
    int2*   epair    = (int2*)  (ws + off); off += (size_t)N_EDGES * sizeof(int2);             // 6.4 MB
    int*    rowptr   = (int*)   (ws + off); off += ((size_t)(N_NODES + 1) * sizeof(int) + 15) & ~15ull;
    int*    deg      = (int*)   (ws + off); off += (size_t)N_NODES * sizeof(int);
    int*    blockSum = (int*)   (ws + off); off += 64 * sizeof(int);
    int*    blockOff = (int*)   (ws + off); off += 64 * sizeof(int);
    // rank overlays hb: rank (3.2 MB) is dead before sgcn_aggregate writes hb.
    int* rank = (int*)hb;

    const int EB = (N_EDGES + 255) / 256;  // 3125

    sgcn_conv_x<<<(N_NODES * D / 8 + 255) / 256, 256, 0, stream>>>(x, (ushort*)xb);
    sgcn_conv_w<<<(D * D / 4 + 255) / 256, 256, 0, stream>>>(W, Wb);

    (void)hipMemsetAsync(deg, 0, (size_t)N_NODES * sizeof(int), stream);
    sgcn_hist_rank<<<EB, 256, 0, stream>>>(ed, deg, rank);
    sgcn_scan1<<<SCAN_NB, 256, 0, stream>>>(deg, blockSum);
    sgcn_scan2<<<1, 64, 0, stream>>>(blockSum, blockOff, rowptr);
    sgcn_scan3<<<SCAN_NB, 256, 0, stream>>>(deg, blockOff, rowptr);
    sgcn_permute<<<EB, 256, 0, stream>>>(es, ed, ev, rowptr, rank, epair);
    sgcn_aggregate<<<2048, 256, 0, stream>>>(xb, rowptr, epair, hb);

    sgcn_gemm_mfma<<<512, 256, 0, stream>>>((const short*)hb, (const short*)Wb, b, out);
}

// Round 6
// 118.709 us; speedup vs baseline: 12.0871x; 1.0395x over previous
//
#include <hip/hip_runtime.h>
#include <hip/hip_bf16.h>

#define N_NODES 50000
#define N_EDGES 800000
#define D 128
#define SCAN_NB 49  // ceil(50000/1024)

typedef __attribute__((ext_vector_type(8))) short short8;
typedef __attribute__((ext_vector_type(4))) float f32x4;
typedef unsigned int uint;
typedef unsigned short ushort;

__device__ __forceinline__ ushort f2bf(float f) {
    // float -> bf16 bits, round-to-nearest-even
    uint u = __float_as_uint(f);
    u += 0x7fffu + ((u >> 16) & 1u);
    return (ushort)(u >> 16);
}

// ---------------- prep: W fp32->bf16 AND zero deg (independent work) ----------------

__global__ __launch_bounds__(256) void sgcn_prep(
    const float* __restrict__ W, ushort* __restrict__ Wb, int* __restrict__ deg)
{
    int t = blockIdx.x * 256 + threadIdx.x;
    if (t < (D * D) / 4) {
        float4 a = reinterpret_cast<const float4*>(W)[t];
        ushort4 s;
        s.x = f2bf(a.x); s.y = f2bf(a.y); s.z = f2bf(a.z); s.w = f2bf(a.w);
        *reinterpret_cast<ushort4*>(Wb + (size_t)t * 4) = s;
    }
    if (t < N_NODES / 4) {  // 12500 int4 stores zero 50000 ints exactly
        reinterpret_cast<int4*>(deg)[t] = make_int4(0, 0, 0, 0);
    }
}

// ---------------- CSR build ----------------

__global__ __launch_bounds__(256) void sgcn_hist_rank(
    const int* __restrict__ dst, int* __restrict__ deg, int* __restrict__ rank)
{
    int e = blockIdx.x * 256 + threadIdx.x;
    if (e < N_EDGES)
        rank[e] = atomicAdd(&deg[dst[e]], 1);
}

__global__ __launch_bounds__(256) void sgcn_scan1(
    const int* __restrict__ deg, int* __restrict__ blockSum)
{
    __shared__ int red[256];
    int tid = threadIdx.x;
    int base = blockIdx.x * 1024 + tid * 4;
    int4 v = make_int4(0, 0, 0, 0);
    if (base < N_NODES) v = *reinterpret_cast<const int4*>(deg + base);
    red[tid] = v.x + v.y + v.z + v.w;
    __syncthreads();
    for (int off = 128; off > 0; off >>= 1) {
        if (tid < off) red[tid] += red[tid + off];
        __syncthreads();
    }
    if (tid == 0) blockSum[blockIdx.x] = red[0];
}

// Fused: per-block offset (reduce blockSum[0..blockIdx)) + local exclusive scan.
__global__ __launch_bounds__(256) void sgcn_scan3f(
    const int* __restrict__ deg, const int* __restrict__ blockSum,
    int* __restrict__ rowptr)
{
    __shared__ int part[256];
    __shared__ int off0;
    int tid = threadIdx.x;
    if (tid < 64) {
        int v = (tid < blockIdx.x) ? blockSum[tid] : 0;  // blockIdx.x <= 48
#pragma unroll
        for (int o = 32; o > 0; o >>= 1) v += __shfl_down(v, o);
        if (tid == 0) off0 = v;
    }
    int base = blockIdx.x * 1024 + tid * 4;
    int4 v = make_int4(0, 0, 0, 0);
    if (base < N_NODES) v = *reinterpret_cast<const int4*>(deg + base);
    int s = v.x + v.y + v.z + v.w;
    part[tid] = s;
    __syncthreads();
    for (int off = 1; off < 256; off <<= 1) {
        int mine  = part[tid];
        int other = (tid >= off) ? part[tid - off] : 0;
        __syncthreads();
        part[tid] = mine + other;
        __syncthreads();
    }
    int run = off0 + ((tid == 0) ? 0 : part[tid - 1]);
    if (base < N_NODES) {
        int4 r;
        r.x = run;
        r.y = run + v.x;
        r.z = r.y + v.y;
        r.w = r.z + v.z;
        *reinterpret_cast<int4*>(rowptr + base) = r;
        if (base + 4 == N_NODES) rowptr[N_NODES] = r.w + v.w;
    }
}

__global__ __launch_bounds__(256) void sgcn_permute(
    const int* __restrict__ src, const int* __restrict__ dst,
    const float* __restrict__ val, const int* __restrict__ rowptr,
    const int* __restrict__ rank, int2* __restrict__ epair)
{
    int e = blockIdx.x * 256 + threadIdx.x;
    if (e < N_EDGES) {
        int pos = rowptr[dst[e]] + rank[e];
        int2 p;
        p.x = src[e];
        p.y = __float_as_int(val[e]);
        epair[pos] = p;
    }
}

// ---------------- MFMA GEMM first: y = x @ W^T (bf16 out) ----------------
// Wave: 16-row x 128-col stripe. A: lane holds x[m0+(l&15)][kb*8+j] (fp32 read,
// bf16 convert inline). B: lane holds W[nt*16+(l&15)][kb*8+j] (row-major Wb).
// C/D: col = l&15 (n), row = kb*4 + r (m). [m89 layout]

__global__ __launch_bounds__(256) void sgcn_gemm_y(
    const float* __restrict__ x, const ushort* __restrict__ Wb,
    ushort* __restrict__ y)
{
    int wave = threadIdx.x >> 6;
    int lane = threadIdx.x & 63;
    int lm = lane & 15;
    int kb = lane >> 4;

    short8 bfr[8][4];
#pragma unroll
    for (int nt = 0; nt < 8; ++nt)
#pragma unroll
        for (int kk = 0; kk < 4; ++kk)
            bfr[nt][kk] = *reinterpret_cast<const short8*>(
                Wb + (nt * 16 + lm) * D + kk * 32 + kb * 8);

    const int nMT = N_NODES / 16;  // 3125
    int mt0 = blockIdx.x * 4 + wave;
    int strideMT = gridDim.x * 4;
    for (int mt = mt0; mt < nMT; mt += strideMT) {
        int m0 = mt * 16;
        const float* xrow = x + (long)(m0 + lm) * D + kb * 8;
        short8 afr[4];
#pragma unroll
        for (int kk = 0; kk < 4; ++kk) {
            float4 a = *reinterpret_cast<const float4*>(xrow + kk * 32);
            float4 c = *reinterpret_cast<const float4*>(xrow + kk * 32 + 4);
            short8 s;
            s[0] = (short)f2bf(a.x); s[1] = (short)f2bf(a.y);
            s[2] = (short)f2bf(a.z); s[3] = (short)f2bf(a.w);
            s[4] = (short)f2bf(c.x); s[5] = (short)f2bf(c.y);
            s[6] = (short)f2bf(c.z); s[7] = (short)f2bf(c.w);
            afr[kk] = s;
        }
#pragma unroll
        for (int nt = 0; nt < 8; ++nt) {
            f32x4 acc = {0.f, 0.f, 0.f, 0.f};
#pragma unroll
            for (int kk = 0; kk < 4; ++kk)
                acc = __builtin_amdgcn_mfma_f32_16x16x32_bf16(afr[kk], bfr[nt][kk], acc, 0, 0, 0);
            ushort* yp = y + (long)(m0 + kb * 4) * D + nt * 16 + lm;
#pragma unroll
            for (int r = 0; r < 4; ++r)
                yp[(long)r * D] = f2bf(acc[r]);
        }
    }
}

// ---------------- Aggregation over y, fused bias+relu ----------------
// yb is [N][64] uints; uint = channels {2*lane, 2*lane+1} packed bf16.

__device__ __forceinline__ float bflo(uint u) { return __uint_as_float(u << 16); }
__device__ __forceinline__ float bfhi(uint u) { return __uint_as_float(u & 0xffff0000u); }

__global__ __launch_bounds__(256) void sgcn_aggregate(
    const uint* __restrict__ yb, const int* __restrict__ rowptr,
    const int2* __restrict__ epair, const float* __restrict__ bias,
    float* __restrict__ out)
{
    int gw   = (blockIdx.x * 256 + threadIdx.x) >> 6;
    int lane = threadIdx.x & 63;
    int nW   = (gridDim.x * 256) >> 6;
    float2 bv = *reinterpret_cast<const float2*>(bias + lane * 2);
    for (int n = gw; n < N_NODES; n += nW) {
        int j0 = rowptr[n], j1 = rowptr[n + 1];
        float ax = 0.f, ay = 0.f;
        int j = j0;
        for (; j + 8 <= j1; j += 8) {
#pragma unroll
            for (int q = 0; q < 8; ++q) {
                int2 p = epair[j + q];
                uint u = yb[(long)p.x * 64 + lane];
                float v = __int_as_float(p.y);
                ax += v * bflo(u);
                ay += v * bfhi(u);
            }
        }
        for (; j < j1; ++j) {
            int2 p = epair[j];
            uint u = yb[(long)p.x * 64 + lane];
            float v = __int_as_float(p.y);
            ax += v * bflo(u);
            ay += v * bfhi(u);
        }
        float2 r;
        r.x = fmaxf(ax + bv.x, 0.f);
        r.y = fmaxf(ay + bv.y, 0.f);
        *reinterpret_cast<float2*>(out + (long)n * D + lane * 2) = r;
    }
}

extern "C" void kernel_launch(void* const* d_in, const int* in_sizes, int n_in,
                              void* d_out, int out_size, void* d_ws, size_t ws_size,
                              hipStream_t stream) {
    const float* x   = (const float*)d_in[0];
    const int*   es  = (const int*)d_in[1];
    const int*   ed  = (const int*)d_in[2];
    const float* ev  = (const float*)d_in[3];
    const float* W   = (const float*)d_in[4];
    const float* b   = (const float*)d_in[5];
    float* out = (float*)d_out;

    // Workspace layout (16B-aligned fields), total ~19.5 MB
    char* ws = (char*)d_ws;
    size_t off = 0;
    uint*   yb       = (uint*)  (ws + off); off += (size_t)N_NODES * (D / 2) * sizeof(uint);   // 12.8 MB
    ushort* Wb       = (ushort*)(ws + off); off += (size_t)D * D * sizeof(ushort);             // 32 KB
    int2*   epair    = (int2*)  (ws + off); off += (size_t)N_EDGES * sizeof(int2);             // 6.4 MB
    int*    rowptr   = (int*)   (ws + off); off += ((size_t)(N_NODES + 1) * sizeof(int) + 15) & ~15ull;
    int*    deg      = (int*)   (ws + off); off += (size_t)N_NODES * sizeof(int);
    int*    blockSum = (int*)   (ws + off); off += 64 * sizeof(int);
    // rank overlays d_out: rank is dead before sgcn_aggregate (sole writer of out).
    int* rank = (int*)d_out;

    const int EB = (N_EDGES + 255) / 256;  // 3125

    sgcn_prep<<<64, 256, 0, stream>>>(W, Wb, deg);
    sgcn_gemm_y<<<512, 256, 0, stream>>>(x, Wb, (ushort*)yb);
    sgcn_hist_rank<<<EB, 256, 0, stream>>>(ed, deg, rank);
    sgcn_scan1<<<SCAN_NB, 256, 0, stream>>>(deg, blockSum);
    sgcn_scan3f<<<SCAN_NB, 256, 0, stream>>>(deg, blockSum, rowptr);
    sgcn_permute<<<EB, 256, 0, stream>>>(es, ed, ev, rowptr, rank, epair);
    sgcn_aggregate<<<2048, 256, 0, stream>>>(yb, rowptr, epair, b, out);
}